// Round 1
// baseline (427.277 us; speedup 1.0000x reference)
//
#include <hip/hip_runtime.h>
#include <hip/hip_bf16.h>

// GCN link predictor — pipeline (R9):
//   prep:  WT1/WT2 = fp16(W^T), cursor init                        [1 launch]
//   K1:    blocks [0,SB): bucket-scatter edges; [SB,SB+GB): gemm1 h1=fp16(x@W1) (unscaled)
//   K2:    per-bucket CSR finalize (rowptr/deg/dinv/adj)
//   agg1:  hrelu = fp16(relu(dinv_i*(h1_i*dinv_i + sum_j h1_j*dinv_j) + b1))
//   gemm2: g2 = fp16((hrelu @ W2) * dinv)
//   agg2:  z = fp16(dinv*(g2_self + sum g2[adj]) + b2)
//   K5:    decode: out[e] = dot(z[a], z[b])
//
// R2: bucket CSR build (kills 105 MB partial-line scatter).
// R3/R4: agg is L2-miss byte-rate bound (~3.4 TB/s, FETCH = 8 XCD x ~24 MB
//        compulsory floor — invariant across 4 kernel shapes). 16-bit g halves it.
// R5: MFMA f16 GEMMs; fp16 everywhere 16-bit.
// R6: gemm dbuf + BM=64.
// R7: K3 (agg1+gemm2 LDS fusion) REGRESSED (occupancy/serialization). Reverted.
// R8: single prep launch, scatter||gemm1, EPB 8192. 377 us.
// R9: barrier-free GEMMs. K1 counters showed MfmaUtil 3.2 / VALU 5.5 / HBM 15% /
//     Occ 28% — pure latency+barrier bound (8 K-iters, vmcnt(0) drain per iter,
//     35 KB LDS -> 4 blocks/CU). B (WT) is L1/L2-resident for all blocks and its
//     frag is a contiguous 16-B/lane load; A frag loaded direct from global and
//     cvt in regs. No LDS, no __syncthreads in gemm role; TLP hides latency.

#define DH 128
#define BUCKET_BITS 8
#define CAP 5120            // per-bucket edge capacity; mean 4096 -> 16 sigma slack
#define EPB 8192            // edges per block in scatter role
#define GBM 64              // gemm rows per block
#define NPB 8               // agg nodes per block

typedef _Float16 half8 __attribute__((ext_vector_type(8)));
typedef float floatx4 __attribute__((ext_vector_type(4)));

__device__ __forceinline__ float4 h4f(uint2 uu) {
    union { uint2 u; _Float16 h[4]; } c; c.u = uu;
    return make_float4((float)c.h[0], (float)c.h[1], (float)c.h[2], (float)c.h[3]);
}

// ---------------- prep: weight transpose+cast + cursor init ----------------

__global__ __launch_bounds__(256) void prep_kernel(
    const float* __restrict__ W1, _Float16* __restrict__ WT1,
    const float* __restrict__ W2, _Float16* __restrict__ WT2,
    int* __restrict__ cursor, int nt1, int nt2) {
    __shared__ float T[32][132];
    int b = blockIdx.x, t = threadIdx.x;
    const float* W; _Float16* WT; int K, tile;
    if (b < nt1)            { W = W1; WT = WT1; K = nt1 * 32; tile = b; }
    else if (b < nt1 + nt2) { W = W2; WT = WT2; K = nt2 * 32; tile = b - nt1; }
    else { int i = (b - nt1 - nt2) * 256 + t; cursor[i] = i * CAP; return; }
    int k0 = tile * 32;
    int kr = t >> 3, c0 = (t & 7) * 16;
#pragma unroll
    for (int j = 0; j < 4; j++) {
        float4 v = *(const float4*)&W[(size_t)(k0 + kr) * DH + c0 + j * 4];
        T[kr][c0 + j * 4 + 0] = v.x;
        T[kr][c0 + j * 4 + 1] = v.y;
        T[kr][c0 + j * 4 + 2] = v.z;
        T[kr][c0 + j * 4 + 3] = v.w;
    }
    __syncthreads();
    int n = t >> 1, ko = (t & 1) * 16;
    union { _Float16 h[16]; uint4 u4[2]; } p;
#pragma unroll
    for (int j = 0; j < 16; j++) p.h[j] = (_Float16)T[ko + j][n];
    *(uint4*)&WT[(size_t)n * K + k0 + ko]     = p.u4[0];
    *(uint4*)&WT[(size_t)n * K + k0 + ko + 8] = p.u4[1];
}

// ---------------- K1: scatter (blocks [0,SB)) + gemm1 (blocks [SB,SB+GB)) ------
// gemm1: h1[m][n] = fp16(sum_k x[m][k]*W1[k][n])  (unscaled; dinv applied in agg1)
// scatter: bucket = dst>>8; packed = src | (dst&255)<<17  (valid N <= 131072)
// gemm role is barrier-free: A frag direct from x (fp32->fp16 in regs),
// B frag direct from WT (L1/L2-resident, identical for all blocks).

__global__ __launch_bounds__(256) void k1_kernel(
    const float* __restrict__ A, const _Float16* __restrict__ WT,
    _Float16* __restrict__ out, int M, int K, int SB,
    const int* __restrict__ src, const int* __restrict__ dst, int E,
    int* __restrict__ cursor, int* __restrict__ pairs) {
    __shared__ int hist[512];
    __shared__ int base[512];
    int t = threadIdx.x;

    if (blockIdx.x < (unsigned)SB) {
        // ---- scatter role ----
        int e0 = blockIdx.x * EPB;
        hist[t] = 0; hist[t + 256] = 0;
        __syncthreads();
        int dc[EPB / 256];
#pragma unroll
        for (int r = 0; r < EPB / 256; r++) {
            int i = e0 + r * 256 + t;
            int d = -1;
            if (i < E) { d = dst[i]; atomicAdd(&hist[d >> BUCKET_BITS], 1); }
            dc[r] = d;
        }
        __syncthreads();
#pragma unroll
        for (int b = t; b < 512; b += 256) {
            int h = hist[b];
            base[b] = h ? atomicAdd(&cursor[b], h) : 0;
        }
        __syncthreads();
        hist[t] = 0; hist[t + 256] = 0;
        __syncthreads();
#pragma unroll
        for (int r = 0; r < EPB / 256; r++) {
            int i = e0 + r * 256 + t;
            int d = dc[r];
            if (d >= 0) {
                int b = d >> BUCKET_BITS;
                int rk = atomicAdd(&hist[b], 1);
                pairs[base[b] + rk] = src[i] | ((d & 255) << 17);
            }
        }
        return;
    }

    // ---- gemm role (barrier-free) ----
    int w = t >> 6, l = t & 63;
    int r = l & 15, q = l >> 4;
    int m0 = (blockIdx.x - SB) * GBM;
    int m = m0 + w * 16 + r;
    const float* ap = A + (size_t)(m < M ? m : 0) * K + q * 8;
    const _Float16* bp = WT + (size_t)r * K + q * 8;

    floatx4 acc[8];
#pragma unroll
    for (int nt = 0; nt < 8; nt++) acc[nt] = (floatx4)0.f;

    float4 f0 = *(const float4*)(ap);
    float4 f1 = *(const float4*)(ap + 4);
    for (int k0 = 0; k0 < K; k0 += 32) {
        union { _Float16 h[8]; half8 v; } a;
        a.h[0] = (_Float16)f0.x; a.h[1] = (_Float16)f0.y;
        a.h[2] = (_Float16)f0.z; a.h[3] = (_Float16)f0.w;
        a.h[4] = (_Float16)f1.x; a.h[5] = (_Float16)f1.y;
        a.h[6] = (_Float16)f1.z; a.h[7] = (_Float16)f1.w;
        if (k0 + 32 < K) {  // prefetch next A frag; B loads issue independently
            f0 = *(const float4*)(ap + k0 + 32);
            f1 = *(const float4*)(ap + k0 + 36);
        }
#pragma unroll
        for (int nt = 0; nt < 8; nt++) {
            half8 bfr = *(const half8*)(bp + (size_t)nt * 16 * K + k0);
            acc[nt] = __builtin_amdgcn_mfma_f32_16x16x32_f16(bfr, a.v, acc[nt], 0, 0, 0);
        }
    }
    if (m < M) {
#pragma unroll
        for (int nt = 0; nt < 8; nt++) {
            union { _Float16 h[4]; uint2 u; } p;
#pragma unroll
            for (int reg = 0; reg < 4; reg++)
                p.h[reg] = (_Float16)acc[nt][reg];
            *(uint2*)&out[(size_t)m * DH + nt * 16 + q * 4] = p.u;
        }
    }
}

// ---------------- K2: per-bucket CSR finalize ----------------

__global__ __launch_bounds__(256) void bucket_build_kernel(
    const int* __restrict__ pairs, const int* __restrict__ cursor,
    int* __restrict__ rowptr, int* __restrict__ deg, float* __restrict__ dinv,
    int* __restrict__ adj, int N) {
    __shared__ int cnt[256];
    __shared__ int sc[256];
    __shared__ int basep[256];
    int b = blockIdx.x;
    int t = threadIdx.x;
    int nb0 = b << BUCKET_BITS;
    int p0 = b * CAP;
    int p1 = cursor[b];
    cnt[t] = 0;
    __syncthreads();
    for (int i = p0 + t; i < p1; i += 256)
        atomicAdd(&cnt[pairs[i] >> 17], 1);
    __syncthreads();
    int c = cnt[t];
    sc[t] = c;
    __syncthreads();
    for (int off = 1; off < 256; off <<= 1) {
        int u = (t >= off) ? sc[t - off] : 0;
        __syncthreads();
        sc[t] += u;
        __syncthreads();
    }
    int ex = sc[t] - c;
    int node = nb0 + t;
    if (node < N) {
        rowptr[node] = p0 + ex;
        deg[node]    = c;
        dinv[node]   = rsqrtf((float)(c + 1));
    }
    basep[t] = p0 + ex;
    cnt[t] = 0;
    __syncthreads();
    for (int i = p0 + t; i < p1; i += 256) {
        int v = pairs[i];
        int li = v >> 17;
        int rk = atomicAdd(&cnt[li], 1);
        adj[basep[li] + rk] = v & 0x1FFFF;
    }
}

// ---------------- agg (templated) ----------------
// SCALED=1 (agg1): acc = h1_i*dinv_i + sum_j h1_j*dinv_j;  out = relu(acc*dinv_i + b)
// SCALED=0 (agg2): acc = g2_i + sum_j g2_j (g2 pre-scaled);  out = acc*dinv_i + b
// 32-lane group per node, uint2 (4 halves)/lane; 4-edge unroll, 4 fp32 acc chains.

template <int SCALED>
__global__ __launch_bounds__(256) void agg_kernel(
    const _Float16* __restrict__ g, const int* __restrict__ rowptr,
    const int* __restrict__ deg, const int* __restrict__ adj,
    const float* __restrict__ dinv, const float* __restrict__ bias,
    _Float16* __restrict__ out, int N) {
    int grp = threadIdx.x >> 5;
    int l   = threadIdx.x & 31;
    int c4  = l * 4;
    int i = blockIdx.x * NPB + grp;
    if (i >= N) return;
    int r0 = rowptr[i];
    int d  = deg[i];
    float dv = dinv[i];
    float4 a0 = h4f(*(const uint2*)(g + (size_t)i * DH + c4));
    if (SCALED) { a0.x *= dv; a0.y *= dv; a0.z *= dv; a0.w *= dv; }
    float4 a1 = make_float4(0.f, 0.f, 0.f, 0.f);
    float4 a2 = make_float4(0.f, 0.f, 0.f, 0.f);
    float4 a3 = make_float4(0.f, 0.f, 0.f, 0.f);
    int r = 0;
    for (; r + 4 <= d; r += 4) {
        int j0 = adj[r0 + r],     j1 = adj[r0 + r + 1];
        int j2 = adj[r0 + r + 2], j3 = adj[r0 + r + 3];
        float4 v0 = h4f(*(const uint2*)(g + (size_t)j0 * DH + c4));
        float4 v1 = h4f(*(const uint2*)(g + (size_t)j1 * DH + c4));
        float4 v2 = h4f(*(const uint2*)(g + (size_t)j2 * DH + c4));
        float4 v3 = h4f(*(const uint2*)(g + (size_t)j3 * DH + c4));
        if (SCALED) {
            float d0 = dinv[j0], d1 = dinv[j1], d2 = dinv[j2], d3 = dinv[j3];
            a0.x = fmaf(v0.x, d0, a0.x); a0.y = fmaf(v0.y, d0, a0.y);
            a0.z = fmaf(v0.z, d0, a0.z); a0.w = fmaf(v0.w, d0, a0.w);
            a1.x = fmaf(v1.x, d1, a1.x); a1.y = fmaf(v1.y, d1, a1.y);
            a1.z = fmaf(v1.z, d1, a1.z); a1.w = fmaf(v1.w, d1, a1.w);
            a2.x = fmaf(v2.x, d2, a2.x); a2.y = fmaf(v2.y, d2, a2.y);
            a2.z = fmaf(v2.z, d2, a2.z); a2.w = fmaf(v2.w, d2, a2.w);
            a3.x = fmaf(v3.x, d3, a3.x); a3.y = fmaf(v3.y, d3, a3.y);
            a3.z = fmaf(v3.z, d3, a3.z); a3.w = fmaf(v3.w, d3, a3.w);
        } else {
            a0.x += v0.x; a0.y += v0.y; a0.z += v0.z; a0.w += v0.w;
            a1.x += v1.x; a1.y += v1.y; a1.z += v1.z; a1.w += v1.w;
            a2.x += v2.x; a2.y += v2.y; a2.z += v2.z; a2.w += v2.w;
            a3.x += v3.x; a3.y += v3.y; a3.z += v3.z; a3.w += v3.w;
        }
    }
    for (; r < d; r++) {
        int j = adj[r0 + r];
        float4 v = h4f(*(const uint2*)(g + (size_t)j * DH + c4));
        float dj = SCALED ? dinv[j] : 1.0f;
        a0.x = fmaf(v.x, dj, a0.x); a0.y = fmaf(v.y, dj, a0.y);
        a0.z = fmaf(v.z, dj, a0.z); a0.w = fmaf(v.w, dj, a0.w);
    }
    a0.x += a1.x + a2.x + a3.x;
    a0.y += a1.y + a2.y + a3.y;
    a0.z += a1.z + a2.z + a3.z;
    a0.w += a1.w + a2.w + a3.w;
    float4 bv = *(const float4*)(bias + c4);
    float sx = a0.x * dv + bv.x;
    float sy = a0.y * dv + bv.y;
    float sz = a0.z * dv + bv.z;
    float sw = a0.w * dv + bv.w;
    if (SCALED) {
        sx = fmaxf(sx, 0.f); sy = fmaxf(sy, 0.f);
        sz = fmaxf(sz, 0.f); sw = fmaxf(sw, 0.f);
    }
    union { _Float16 h[4]; uint2 u; } p;
    p.h[0] = (_Float16)sx; p.h[1] = (_Float16)sy;
    p.h[2] = (_Float16)sz; p.h[3] = (_Float16)sw;
    *(uint2*)(out + (size_t)i * DH + c4) = p.u;
}

// ---------------- gemm2: g2 = fp16((hrelu @ W2) * dinv), barrier-free ----------

__global__ __launch_bounds__(256) void gemm2_kernel(
    const _Float16* __restrict__ A, const _Float16* __restrict__ WT,
    const float* __restrict__ dinv, _Float16* __restrict__ out,
    int M, int K) {
    int t = threadIdx.x;
    int w = t >> 6, l = t & 63;
    int r = l & 15, q = l >> 4;
    int m0 = blockIdx.x * GBM;
    int m = m0 + w * 16 + r;
    const _Float16* ap = A + (size_t)(m < M ? m : 0) * K + q * 8;
    const _Float16* bp = WT + (size_t)r * K + q * 8;

    floatx4 acc[8];
#pragma unroll
    for (int nt = 0; nt < 8; nt++) acc[nt] = (floatx4)0.f;

    for (int k0 = 0; k0 < K; k0 += 32) {
        half8 afr = *(const half8*)(ap + k0);
#pragma unroll
        for (int nt = 0; nt < 8; nt++) {
            half8 bfr = *(const half8*)(bp + (size_t)nt * 16 * K + k0);
            acc[nt] = __builtin_amdgcn_mfma_f32_16x16x32_f16(bfr, afr, acc[nt], 0, 0, 0);
        }
    }
    if (m < M) {
        float dv = dinv[m];
#pragma unroll
        for (int nt = 0; nt < 8; nt++) {
            union { _Float16 h[4]; uint2 u; } p;
#pragma unroll
            for (int reg = 0; reg < 4; reg++)
                p.h[reg] = (_Float16)(acc[nt][reg] * dv);
            *(uint2*)&out[(size_t)m * DH + nt * 16 + q * 4] = p.u;
        }
    }
}

// ---------------- K5: decode: out[e] = dot(z[a], z[b]) over 128 (z fp16) ----------

__global__ __launch_bounds__(256) void decode_kernel(
    const _Float16* __restrict__ z, const int* __restrict__ ea, const int* __restrict__ eb,
    float* __restrict__ out, int EL) {
    int e = blockIdx.x * 8 + (threadIdx.x >> 5);
    int l = threadIdx.x & 31;
    if (e >= EL) return;
    int a = ea[e], b = eb[e];
    float4 va = h4f(*(const uint2*)(z + (size_t)a * DH + l * 4));
    float4 vb = h4f(*(const uint2*)(z + (size_t)b * DH + l * 4));
    float acc = va.x * vb.x + va.y * vb.y + va.z * vb.z + va.w * vb.w;
#pragma unroll
    for (int off = 16; off > 0; off >>= 1)
        acc += __shfl_down(acc, off, 32);
    if (l == 0) out[e] = acc;
}

// ---------------- Launch ----------------

extern "C" void kernel_launch(void* const* d_in, const int* in_sizes, int n_in,
                              void* d_out, int out_size, void* d_ws, size_t ws_size,
                              hipStream_t stream) {
    const float* x   = (const float*)d_in[0];
    const int*   ei  = (const int*)d_in[1];
    const int*   eli = (const int*)d_in[2];
    const float* W1  = (const float*)d_in[3];
    const float* b1  = (const float*)d_in[4];
    const float* W2  = (const float*)d_in[5];
    const float* b2  = (const float*)d_in[6];
    float* out = (float*)d_out;

    int DHv = in_sizes[4];                 // 128
    int DIN = in_sizes[3] / DHv;           // 256
    int N   = in_sizes[0] / DIN;           // 100000
    int E   = in_sizes[1] / 2;             // 1600000
    int EL  = in_sizes[2] / 2;             // 200000
    const int* src = ei;
    const int* dst = ei + E;
    const int* ea = eli;
    const int* eb = eli + EL;

    int NB = (N + 255) >> BUCKET_BITS;     // 391 buckets
    int SB = (E + EPB - 1) / EPB;          // 196 scatter blocks
    int GB = (N + GBM - 1) / GBM;          // 1563 gemm blocks

    // workspace carve-up (256B aligned)
    char* ws = (char*)d_ws;
    size_t off = 0;
    auto alloc = [&](size_t bytes) {
        void* p = ws + off;
        off += (bytes + 255) & ~(size_t)255;
        return p;
    };
    int*      cursor = (int*)alloc(512 * 4);
    int*      rowptr = (int*)alloc((size_t)N * 4);
    int*      deg    = (int*)alloc((size_t)N * 4);
    float*    dinv   = (float*)alloc((size_t)N * 4);
    int*      adj    = (int*)alloc((size_t)NB * CAP * 4);      // bucketed, with gaps
    _Float16* WT1    = (_Float16*)alloc((size_t)DIN * DHv * 2);
    _Float16* WT2    = (_Float16*)alloc((size_t)DHv * DHv * 2);
    _Float16* gbuf   = (_Float16*)alloc((size_t)N * DH * 2);   // h1 -> g2
    _Float16* hbuf   = (_Float16*)alloc((size_t)N * DH * 2);   // hrelu -> z
    int*      pairs  = (int*)hbuf;   // 8 MB staging; consumed by K2 before agg1 writes hbuf

    int nt1 = DIN / 32, nt2 = DHv / 32;
    // prep: WT1, WT2, cursor
    prep_kernel<<<nt1 + nt2 + 2, 256, 0, stream>>>(W1, WT1, W2, WT2, cursor, nt1, nt2);
    // K1: scatter (first SB blocks) || gemm1 h1 = fp16(x@W1) unscaled
    k1_kernel<<<SB + GB, 256, 0, stream>>>(x, WT1, gbuf, N, DIN, SB,
                                           src, dst, E, cursor, pairs);
    // K2: CSR finalize
    bucket_build_kernel<<<NB, 256, 0, stream>>>(pairs, cursor, rowptr, deg, dinv, adj, N);
    // agg1: hrelu (per-edge dinv scaling, relu)
    agg_kernel<1><<<(N + NPB - 1) / NPB, 256, 0, stream>>>(gbuf, rowptr, deg, adj, dinv, b1, hbuf, N);
    // gemm2: g2 = fp16((hrelu @ W2) * dinv)
    gemm2_kernel<<<GB, 256, 0, stream>>>(hbuf, WT2, dinv, gbuf, N, DHv);
    // agg2: z = fp16(dinv*(g2_self + sum g2[adj]) + b2)
    agg_kernel<0><<<(N + NPB - 1) / NPB, 256, 0, stream>>>(gbuf, rowptr, deg, adj, dinv, b2, hbuf, N);
    // decode
    decode_kernel<<<(EL + 7) / 8, 256, 0, stream>>>(hbuf, ea, eb, out, EL);
}

// Round 2
// 372.918 us; speedup vs baseline: 1.1458x; 1.1458x over previous
//
#include <hip/hip_runtime.h>
#include <hip/hip_bf16.h>

// GCN link predictor — pipeline (R10):
//   prep:  WT1/WT2 = fp16(W^T), cursor init                        [1 launch]
//   K1:    blocks [0,SB): bucket-scatter edges; [SB,SB+GB): gemm1 h1=fp16(x@W1) (unscaled)
//   K2:    per-bucket CSR finalize (rowptr/deg/dinv/adj)
//   agg1:  hrelu = fp16(relu(dinv_i*(h1_i*dinv_i + sum_j h1_j*dinv_j) + b1))
//   gemm2: g2 = fp16((hrelu @ W2) * dinv)
//   agg2:  z = fp16(dinv*(g2_self + sum g2[adj]) + b2)
//   K5:    decode: out[e] = dot(z[a], z[b])
//
// R2: bucket CSR build. R3/R4: agg is L2-miss byte-rate bound (compulsory floor).
// R5: MFMA f16 GEMMs. R6: dbuf BM=64. R7: agg+gemm fusion regressed (reverted).
// R8: scatter||gemm1 single kernel, 377 us (K1=75).
// R9: barrier-free gemm with per-MFMA global B-loads REGRESSED (K1 104 us):
//     latency-bound, ~2KB/CU in flight (Little's law), MfmaUtil 2.4%.
// R10: burst-issue structure. gemm1: full B (64KB) staged to LDS ONCE per block
//     (pad stride 264 halves -> optimal 8-cycle b128 reads), full A K-panel
//     (16x dwordx4) into regs in one burst; ONE barrier; then pure ds_read+MFMA.
//     ~512B/thread in flight before first wait -> HBM-drain bound, not latency.
//     gemm2 same shape (B 32KB staged once, A 4x dwordx4, 1 barrier).

#define DH 128
#define BUCKET_BITS 8
#define CAP 5120            // per-bucket edge capacity; mean 4096 -> 16 sigma slack
#define EPB 8192            // edges per block in scatter role
#define GBM 64              // gemm rows per block
#define NPB 8               // agg nodes per block
#define BP1 264             // gemm1 B LDS row stride (halves): 528B, 16B-aligned, 8-lane/bank
#define BP2 136             // gemm2 B LDS row stride (halves): 272B, 16B-aligned, 8-lane/bank

typedef _Float16 half8 __attribute__((ext_vector_type(8)));
typedef float floatx4 __attribute__((ext_vector_type(4)));

__device__ __forceinline__ float4 h4f(uint2 uu) {
    union { uint2 u; _Float16 h[4]; } c; c.u = uu;
    return make_float4((float)c.h[0], (float)c.h[1], (float)c.h[2], (float)c.h[3]);
}

// ---------------- prep: weight transpose+cast + cursor init ----------------

__global__ __launch_bounds__(256) void prep_kernel(
    const float* __restrict__ W1, _Float16* __restrict__ WT1,
    const float* __restrict__ W2, _Float16* __restrict__ WT2,
    int* __restrict__ cursor, int nt1, int nt2) {
    __shared__ float T[32][132];
    int b = blockIdx.x, t = threadIdx.x;
    const float* W; _Float16* WT; int K, tile;
    if (b < nt1)            { W = W1; WT = WT1; K = nt1 * 32; tile = b; }
    else if (b < nt1 + nt2) { W = W2; WT = WT2; K = nt2 * 32; tile = b - nt1; }
    else { int i = (b - nt1 - nt2) * 256 + t; cursor[i] = i * CAP; return; }
    int k0 = tile * 32;
    int kr = t >> 3, c0 = (t & 7) * 16;
#pragma unroll
    for (int j = 0; j < 4; j++) {
        float4 v = *(const float4*)&W[(size_t)(k0 + kr) * DH + c0 + j * 4];
        T[kr][c0 + j * 4 + 0] = v.x;
        T[kr][c0 + j * 4 + 1] = v.y;
        T[kr][c0 + j * 4 + 2] = v.z;
        T[kr][c0 + j * 4 + 3] = v.w;
    }
    __syncthreads();
    int n = t >> 1, ko = (t & 1) * 16;
    union { _Float16 h[16]; uint4 u4[2]; } p;
#pragma unroll
    for (int j = 0; j < 16; j++) p.h[j] = (_Float16)T[ko + j][n];
    *(uint4*)&WT[(size_t)n * K + k0 + ko]     = p.u4[0];
    *(uint4*)&WT[(size_t)n * K + k0 + ko + 8] = p.u4[1];
}

// ---------------- K1: scatter (blocks [0,SB)) + gemm1 (blocks [SB,SB+GB)) ------
// gemm1: h1[m][n] = fp16(sum_k x[m][k]*W1[k][n])  (unscaled; dinv applied in agg1)
// scatter: bucket = dst>>8; packed = src | (dst&255)<<17  (valid N <= 131072)

__global__ __launch_bounds__(256) void k1_kernel(
    const float* __restrict__ A, const _Float16* __restrict__ WT,
    _Float16* __restrict__ out, int M, int K, int SB,
    const int* __restrict__ src, const int* __restrict__ dst, int E,
    int* __restrict__ cursor, int* __restrict__ pairs) {
    __shared__ __attribute__((aligned(16))) union {
        struct { int hist[512]; int base[512]; } s;
        _Float16 b[128 * BP1];                      // 67584 B
    } sm;
    int t = threadIdx.x;

    if (blockIdx.x < (unsigned)SB) {
        // ---- scatter role ----
        int* hist = sm.s.hist;
        int* base = sm.s.base;
        int e0 = blockIdx.x * EPB;
        hist[t] = 0; hist[t + 256] = 0;
        __syncthreads();
        int dc[EPB / 256];
#pragma unroll
        for (int r = 0; r < EPB / 256; r++) {
            int i = e0 + r * 256 + t;
            int d = -1;
            if (i < E) { d = dst[i]; atomicAdd(&hist[d >> BUCKET_BITS], 1); }
            dc[r] = d;
        }
        __syncthreads();
#pragma unroll
        for (int b = t; b < 512; b += 256) {
            int h = hist[b];
            base[b] = h ? atomicAdd(&cursor[b], h) : 0;
        }
        __syncthreads();
        hist[t] = 0; hist[t + 256] = 0;
        __syncthreads();
#pragma unroll
        for (int r = 0; r < EPB / 256; r++) {
            int i = e0 + r * 256 + t;
            int d = dc[r];
            if (d >= 0) {
                int b = d >> BUCKET_BITS;
                int rk = atomicAdd(&hist[b], 1);
                pairs[base[b] + rk] = src[i] | ((d & 255) << 17);
            }
        }
        return;
    }

    // ---- gemm role: burst-issue, one barrier ----
    int w = t >> 6, l = t & 63;
    int r = l & 15, q = l >> 4;
    int m0 = (blockIdx.x - SB) * GBM;
    int m = m0 + w * 16 + r;

    // issue B loads first (16 x dwordx4/thread, coalesced 4KB per wave-instr)
    const uint4* bsrc = (const uint4*)WT;            // 64KB = 4096 chunks of 16B
    uint4 rb[16];
#pragma unroll
    for (int i = 0; i < 16; i++) rb[i] = bsrc[i * 256 + t];

    // then A K-panel (16 x dwordx4/thread) — stays in flight through staging
    const float* ap = A + (size_t)(m < M ? m : 0) * K + q * 8;
    float4 fA[16];
#pragma unroll
    for (int i = 0; i < 8; i++) {
        fA[2 * i]     = *(const float4*)(ap + i * 32);
        fA[2 * i + 1] = *(const float4*)(ap + i * 32 + 4);
    }

    // stage B to padded LDS (waits only on rb: counted vmcnt keeps fA in flight)
#pragma unroll
    for (int i = 0; i < 16; i++) {
        int ci = i * 256 + t;                        // 16B chunk index
        *(uint4*)&sm.b[(ci >> 5) * BP1 + (ci & 31) * 8] = rb[i];
    }
    __syncthreads();

    floatx4 acc[8];
#pragma unroll
    for (int nt = 0; nt < 8; nt++) acc[nt] = (floatx4)0.f;

#pragma unroll
    for (int kk = 0; kk < 8; kk++) {
        union { _Float16 h[8]; half8 v; } a;
        float4 f0 = fA[2 * kk], f1 = fA[2 * kk + 1];
        a.h[0] = (_Float16)f0.x; a.h[1] = (_Float16)f0.y;
        a.h[2] = (_Float16)f0.z; a.h[3] = (_Float16)f0.w;
        a.h[4] = (_Float16)f1.x; a.h[5] = (_Float16)f1.y;
        a.h[6] = (_Float16)f1.z; a.h[7] = (_Float16)f1.w;
        int k0 = kk * 32;
#pragma unroll
        for (int nt = 0; nt < 8; nt++) {
            half8 bfr = *(const half8*)&sm.b[(nt * 16 + r) * BP1 + k0 + q * 8];
            acc[nt] = __builtin_amdgcn_mfma_f32_16x16x32_f16(bfr, a.v, acc[nt], 0, 0, 0);
        }
    }
    if (m < M) {
#pragma unroll
        for (int nt = 0; nt < 8; nt++) {
            union { _Float16 h[4]; uint2 u; } p;
#pragma unroll
            for (int reg = 0; reg < 4; reg++)
                p.h[reg] = (_Float16)acc[nt][reg];
            *(uint2*)&out[(size_t)m * DH + nt * 16 + q * 4] = p.u;
        }
    }
}

// ---------------- K2: per-bucket CSR finalize ----------------

__global__ __launch_bounds__(256) void bucket_build_kernel(
    const int* __restrict__ pairs, const int* __restrict__ cursor,
    int* __restrict__ rowptr, int* __restrict__ deg, float* __restrict__ dinv,
    int* __restrict__ adj, int N) {
    __shared__ int cnt[256];
    __shared__ int sc[256];
    __shared__ int basep[256];
    int b = blockIdx.x;
    int t = threadIdx.x;
    int nb0 = b << BUCKET_BITS;
    int p0 = b * CAP;
    int p1 = cursor[b];
    cnt[t] = 0;
    __syncthreads();
    for (int i = p0 + t; i < p1; i += 256)
        atomicAdd(&cnt[pairs[i] >> 17], 1);
    __syncthreads();
    int c = cnt[t];
    sc[t] = c;
    __syncthreads();
    for (int off = 1; off < 256; off <<= 1) {
        int u = (t >= off) ? sc[t - off] : 0;
        __syncthreads();
        sc[t] += u;
        __syncthreads();
    }
    int ex = sc[t] - c;
    int node = nb0 + t;
    if (node < N) {
        rowptr[node] = p0 + ex;
        deg[node]    = c;
        dinv[node]   = rsqrtf((float)(c + 1));
    }
    basep[t] = p0 + ex;
    cnt[t] = 0;
    __syncthreads();
    for (int i = p0 + t; i < p1; i += 256) {
        int v = pairs[i];
        int li = v >> 17;
        int rk = atomicAdd(&cnt[li], 1);
        adj[basep[li] + rk] = v & 0x1FFFF;
    }
}

// ---------------- agg (templated) ----------------
// SCALED=1 (agg1): acc = h1_i*dinv_i + sum_j h1_j*dinv_j;  out = relu(acc*dinv_i + b)
// SCALED=0 (agg2): acc = g2_i + sum_j g2_j (g2 pre-scaled);  out = acc*dinv_i + b

template <int SCALED>
__global__ __launch_bounds__(256) void agg_kernel(
    const _Float16* __restrict__ g, const int* __restrict__ rowptr,
    const int* __restrict__ deg, const int* __restrict__ adj,
    const float* __restrict__ dinv, const float* __restrict__ bias,
    _Float16* __restrict__ out, int N) {
    int grp = threadIdx.x >> 5;
    int l   = threadIdx.x & 31;
    int c4  = l * 4;
    int i = blockIdx.x * NPB + grp;
    if (i >= N) return;
    int r0 = rowptr[i];
    int d  = deg[i];
    float dv = dinv[i];
    float4 a0 = h4f(*(const uint2*)(g + (size_t)i * DH + c4));
    if (SCALED) { a0.x *= dv; a0.y *= dv; a0.z *= dv; a0.w *= dv; }
    float4 a1 = make_float4(0.f, 0.f, 0.f, 0.f);
    float4 a2 = make_float4(0.f, 0.f, 0.f, 0.f);
    float4 a3 = make_float4(0.f, 0.f, 0.f, 0.f);
    int r = 0;
    for (; r + 4 <= d; r += 4) {
        int j0 = adj[r0 + r],     j1 = adj[r0 + r + 1];
        int j2 = adj[r0 + r + 2], j3 = adj[r0 + r + 3];
        float4 v0 = h4f(*(const uint2*)(g + (size_t)j0 * DH + c4));
        float4 v1 = h4f(*(const uint2*)(g + (size_t)j1 * DH + c4));
        float4 v2 = h4f(*(const uint2*)(g + (size_t)j2 * DH + c4));
        float4 v3 = h4f(*(const uint2*)(g + (size_t)j3 * DH + c4));
        if (SCALED) {
            float d0 = dinv[j0], d1 = dinv[j1], d2 = dinv[j2], d3 = dinv[j3];
            a0.x = fmaf(v0.x, d0, a0.x); a0.y = fmaf(v0.y, d0, a0.y);
            a0.z = fmaf(v0.z, d0, a0.z); a0.w = fmaf(v0.w, d0, a0.w);
            a1.x = fmaf(v1.x, d1, a1.x); a1.y = fmaf(v1.y, d1, a1.y);
            a1.z = fmaf(v1.z, d1, a1.z); a1.w = fmaf(v1.w, d1, a1.w);
            a2.x = fmaf(v2.x, d2, a2.x); a2.y = fmaf(v2.y, d2, a2.y);
            a2.z = fmaf(v2.z, d2, a2.z); a2.w = fmaf(v2.w, d2, a2.w);
            a3.x = fmaf(v3.x, d3, a3.x); a3.y = fmaf(v3.y, d3, a3.y);
            a3.z = fmaf(v3.z, d3, a3.z); a3.w = fmaf(v3.w, d3, a3.w);
        } else {
            a0.x += v0.x; a0.y += v0.y; a0.z += v0.z; a0.w += v0.w;
            a1.x += v1.x; a1.y += v1.y; a1.z += v1.z; a1.w += v1.w;
            a2.x += v2.x; a2.y += v2.y; a2.z += v2.z; a2.w += v2.w;
            a3.x += v3.x; a3.y += v3.y; a3.z += v3.z; a3.w += v3.w;
        }
    }
    for (; r < d; r++) {
        int j = adj[r0 + r];
        float4 v = h4f(*(const uint2*)(g + (size_t)j * DH + c4));
        float dj = SCALED ? dinv[j] : 1.0f;
        a0.x = fmaf(v.x, dj, a0.x); a0.y = fmaf(v.y, dj, a0.y);
        a0.z = fmaf(v.z, dj, a0.z); a0.w = fmaf(v.w, dj, a0.w);
    }
    a0.x += a1.x + a2.x + a3.x;
    a0.y += a1.y + a2.y + a3.y;
    a0.z += a1.z + a2.z + a3.z;
    a0.w += a1.w + a2.w + a3.w;
    float4 bv = *(const float4*)(bias + c4);
    float sx = a0.x * dv + bv.x;
    float sy = a0.y * dv + bv.y;
    float sz = a0.z * dv + bv.z;
    float sw = a0.w * dv + bv.w;
    if (SCALED) {
        sx = fmaxf(sx, 0.f); sy = fmaxf(sy, 0.f);
        sz = fmaxf(sz, 0.f); sw = fmaxf(sw, 0.f);
    }
    union { _Float16 h[4]; uint2 u; } p;
    p.h[0] = (_Float16)sx; p.h[1] = (_Float16)sy;
    p.h[2] = (_Float16)sz; p.h[3] = (_Float16)sw;
    *(uint2*)(out + (size_t)i * DH + c4) = p.u;
}

// ---------------- gemm2: g2 = fp16((hrelu @ W2) * dinv), burst-issue ----------

__global__ __launch_bounds__(256) void gemm2_kernel(
    const _Float16* __restrict__ A, const _Float16* __restrict__ WT,
    const float* __restrict__ dinv, _Float16* __restrict__ out,
    int M, int K) {
    __shared__ __attribute__((aligned(16))) _Float16 Blds[128 * BP2];  // 34816 B
    int t = threadIdx.x;
    int w = t >> 6, l = t & 63;
    int r = l & 15, q = l >> 4;
    int m0 = blockIdx.x * GBM;
    int m = m0 + w * 16 + r;

    const uint4* bsrc = (const uint4*)WT;            // 32KB = 2048 chunks of 16B
    uint4 rb[8];
#pragma unroll
    for (int i = 0; i < 8; i++) rb[i] = bsrc[i * 256 + t];

    const _Float16* ap = A + (size_t)(m < M ? m : 0) * K + q * 8;
    uint4 fa[4];
#pragma unroll
    for (int i = 0; i < 4; i++) fa[i] = *(const uint4*)(ap + i * 32);

#pragma unroll
    for (int i = 0; i < 8; i++) {
        int ci = i * 256 + t;                        // 16 chunks per 128-half row
        *(uint4*)&Blds[(ci >> 4) * BP2 + (ci & 15) * 8] = rb[i];
    }
    __syncthreads();

    floatx4 acc[8];
#pragma unroll
    for (int nt = 0; nt < 8; nt++) acc[nt] = (floatx4)0.f;

#pragma unroll
    for (int kk = 0; kk < 4; kk++) {
        union { uint4 u; half8 v; } a; a.u = fa[kk];
        int k0 = kk * 32;
#pragma unroll
        for (int nt = 0; nt < 8; nt++) {
            half8 bfr = *(const half8*)&Blds[(nt * 16 + r) * BP2 + k0 + q * 8];
            acc[nt] = __builtin_amdgcn_mfma_f32_16x16x32_f16(bfr, a.v, acc[nt], 0, 0, 0);
        }
    }
    if (m < M) {
        float dv = dinv[m];
#pragma unroll
        for (int nt = 0; nt < 8; nt++) {
            union { _Float16 h[4]; uint2 u; } p;
#pragma unroll
            for (int reg = 0; reg < 4; reg++)
                p.h[reg] = (_Float16)(acc[nt][reg] * dv);
            *(uint2*)&out[(size_t)m * DH + nt * 16 + q * 4] = p.u;
        }
    }
}

// ---------------- K5: decode: out[e] = dot(z[a], z[b]) over 128 (z fp16) ----------

__global__ __launch_bounds__(256) void decode_kernel(
    const _Float16* __restrict__ z, const int* __restrict__ ea, const int* __restrict__ eb,
    float* __restrict__ out, int EL) {
    int e = blockIdx.x * 8 + (threadIdx.x >> 5);
    int l = threadIdx.x & 31;
    if (e >= EL) return;
    int a = ea[e], b = eb[e];
    float4 va = h4f(*(const uint2*)(z + (size_t)a * DH + l * 4));
    float4 vb = h4f(*(const uint2*)(z + (size_t)b * DH + l * 4));
    float acc = va.x * vb.x + va.y * vb.y + va.z * vb.z + va.w * vb.w;
#pragma unroll
    for (int off = 16; off > 0; off >>= 1)
        acc += __shfl_down(acc, off, 32);
    if (l == 0) out[e] = acc;
}

// ---------------- Launch ----------------

extern "C" void kernel_launch(void* const* d_in, const int* in_sizes, int n_in,
                              void* d_out, int out_size, void* d_ws, size_t ws_size,
                              hipStream_t stream) {
    const float* x   = (const float*)d_in[0];
    const int*   ei  = (const int*)d_in[1];
    const int*   eli = (const int*)d_in[2];
    const float* W1  = (const float*)d_in[3];
    const float* b1  = (const float*)d_in[4];
    const float* W2  = (const float*)d_in[5];
    const float* b2  = (const float*)d_in[6];
    float* out = (float*)d_out;

    int DHv = in_sizes[4];                 // 128
    int DIN = in_sizes[3] / DHv;           // 256
    int N   = in_sizes[0] / DIN;           // 100000
    int E   = in_sizes[1] / 2;             // 1600000
    int EL  = in_sizes[2] / 2;             // 200000
    const int* src = ei;
    const int* dst = ei + E;
    const int* ea = eli;
    const int* eb = eli + EL;

    int NB = (N + 255) >> BUCKET_BITS;     // 391 buckets
    int SB = (E + EPB - 1) / EPB;          // 196 scatter blocks
    int GB = (N + GBM - 1) / GBM;          // 1563 gemm blocks

    // workspace carve-up (256B aligned)
    char* ws = (char*)d_ws;
    size_t off = 0;
    auto alloc = [&](size_t bytes) {
        void* p = ws + off;
        off += (bytes + 255) & ~(size_t)255;
        return p;
    };
    int*      cursor = (int*)alloc(512 * 4);
    int*      rowptr = (int*)alloc((size_t)N * 4);
    int*      deg    = (int*)alloc((size_t)N * 4);
    float*    dinv   = (float*)alloc((size_t)N * 4);
    int*      adj    = (int*)alloc((size_t)NB * CAP * 4);      // bucketed, with gaps
    _Float16* WT1    = (_Float16*)alloc((size_t)DIN * DHv * 2);
    _Float16* WT2    = (_Float16*)alloc((size_t)DHv * DHv * 2);
    _Float16* gbuf   = (_Float16*)alloc((size_t)N * DH * 2);   // h1 -> g2
    _Float16* hbuf   = (_Float16*)alloc((size_t)N * DH * 2);   // hrelu -> z
    int*      pairs  = (int*)hbuf;   // 8 MB staging; consumed by K2 before agg1 writes hbuf

    int nt1 = DIN / 32, nt2 = DHv / 32;
    // prep: WT1, WT2, cursor
    prep_kernel<<<nt1 + nt2 + 2, 256, 0, stream>>>(W1, WT1, W2, WT2, cursor, nt1, nt2);
    // K1: scatter (first SB blocks) || gemm1 h1 = fp16(x@W1) unscaled
    k1_kernel<<<SB + GB, 256, 0, stream>>>(x, WT1, gbuf, N, DIN, SB,
                                           src, dst, E, cursor, pairs);
    // K2: CSR finalize
    bucket_build_kernel<<<NB, 256, 0, stream>>>(pairs, cursor, rowptr, deg, dinv, adj, N);
    // agg1: hrelu (per-edge dinv scaling, relu)
    agg_kernel<1><<<(N + NPB - 1) / NPB, 256, 0, stream>>>(gbuf, rowptr, deg, adj, dinv, b1, hbuf, N);
    // gemm2: g2 = fp16((hrelu @ W2) * dinv)
    gemm2_kernel<<<GB, 256, 0, stream>>>(hbuf, WT2, dinv, gbuf, N, DHv);
    // agg2: z = fp16(dinv*(g2_self + sum g2[adj]) + b2)
    agg_kernel<0><<<(N + NPB - 1) / NPB, 256, 0, stream>>>(gbuf, rowptr, deg, adj, dinv, b2, hbuf, N);
    // decode
    decode_kernel<<<(EL + 7) / 8, 256, 0, stream>>>(hbuf, ea, eb, out, EL);
}